// Round 3
// baseline (658.118 us; speedup 1.0000x reference)
//
#include <hip/hip_runtime.h>
#include <cstdint>
#include <cstddef>

// ---------------------------------------------------------------------------
// SDHGNN round 11: attn4 grid-occupancy fix. QBLK 64 -> 32 (grid.x 32 -> 64),
// 1024 blocks = 4 blocks/CU = 32 waves/CU (was 2 blocks -> 16 waves, the
// round-9/10 occupancy ceiling). Wave layout (qh 0..1) x (mh 0..3), each wave
// one 16-q-row tile; qt dimension dropped everywhere (regs halve). K/V staged
// per block (traffic doubles; HBM at 6.8% and L2-resident, so affordable).
// Round 10 structure kept: T14 async-STAGE in both passes + gcore, bpermute
// PV, exp2 domain, 3-term scores in both passes (p / top-k margin safe).
// ---------------------------------------------------------------------------

#define NB 2
#define ND 128
#define NH 4
#define NN 2048
#define ND2 256
#define DN (ND*NN)
#define BDN (NB*DN)
// (1/sqrt(32)) * log2(e): scores produced directly in exp2 domain.
#define QK_SCALE 0.2550348623f
#define IN_EPS 1e-3f

typedef unsigned short u16;
typedef __attribute__((ext_vector_type(8))) short short8;
typedef __attribute__((ext_vector_type(4))) float f32x4;

__device__ __forceinline__ u16 f2bf(float f) {
    unsigned u = __float_as_uint(f);
    return (u16)((u + 0x7fffu + ((u >> 16) & 1u)) >> 16);
}
__device__ __forceinline__ float bf2f(u16 h) {
    return __uint_as_float(((unsigned)h) << 16);
}
__device__ __forceinline__ float fexp2(float x) {
#if __has_builtin(__builtin_amdgcn_exp2f)
    return __builtin_amdgcn_exp2f(x);
#else
    return exp2f(x);
#endif
}
__device__ __forceinline__ unsigned cvtpk_bf16(float a, float b) {
    unsigned r;
    asm("v_cvt_pk_bf16_f32 %0, %1, %2" : "=v"(r) : "v"(a), "v"(b));
    return r;
}

// ---------------------------------------------------------------------------
__global__ __launch_bounds__(256) void init_kernel(
    const float* __restrict__ x0in, const float* __restrict__ x1in,
    float* __restrict__ out, int* __restrict__ idx0, int* __restrict__ idx1)
{
    int tid = blockIdx.x * 256 + threadIdx.x;
    const float4* a = (const float4*)x0in;
    const float4* b = (const float4*)x1in;
    float4* o = (float4*)out;
    o[tid] = a[tid];
    o[BDN/4 + tid] = b[tid];
    if (tid < NB*NN) {
        int v = tid & (NN-1);
        idx0[tid] = v;
        idx1[tid] = v;
    }
}

// ---------------------------------------------------------------------------
// weights -> bf16 hi/lo planes with permutations:
//   Wq/Wk/Wv rows permuted o' = h*32+i; Wm cols permuted; W1/W2 unchanged.
// ---------------------------------------------------------------------------
__global__ __launch_bounds__(256) void wrepack2_kernel(
    const float* __restrict__ Wq, const float* __restrict__ Wk,
    const float* __restrict__ Wv, const float* __restrict__ Wm,
    const float* __restrict__ W1, const float* __restrict__ W2,
    const float* __restrict__ bq, const float* __restrict__ bk,
    const float* __restrict__ bv,
    u16* __restrict__ whi, u16* __restrict__ wlo,
    float* __restrict__ bqp, float* __restrict__ bkp, float* __restrict__ bvp)
{
    int e = blockIdx.x * 256 + threadIdx.x;
    if (e < 655360) {
        int l = e / 163840, r = e - l*163840;
        float v;
        if (r < 49152) {
            int m = r >> 14;
            int rr = r & 16383;
            int o = rr >> 7, c = rr & 127;
            int so = (o & 31)*4 + (o >> 5);
            const float* W = (m == 0) ? Wq : ((m == 1) ? Wk : Wv);
            v = W[l*16384 + so*128 + c];
        } else if (r < 65536) {
            int rr = r - 49152;
            int o = rr >> 7, c = rr & 127;
            int sc = (c & 31)*4 + (c >> 5);
            v = Wm[l*16384 + o*128 + sc];
        } else if (r < 131072) v = W1[l*65536 + r - 65536];
        else                   v = W2[l*32768 + r - 131072];
        u16 hb = f2bf(v);
        whi[e] = hb;
        wlo[e] = f2bf(v - bf2f(hb));
    } else if (e < 656896) {
        int eb = e - 655360;
        int l = eb / 384, rr = eb % 384;
        int which = rr >> 7, o = rr & 127;
        int so = (o & 31)*4 + (o >> 5);
        float v = (which == 0 ? bq : (which == 1 ? bk : bv))[l*128 + so];
        (which == 0 ? bqp : (which == 1 ? bkp : bvp))[l*128 + o] = v;
    }
}

// ---------------------------------------------------------------------------
// fp32 [z][128][NN] -> bf16 hi/lo planes [z][n][128] (initial x planes)
// ---------------------------------------------------------------------------
__global__ __launch_bounds__(256) void repack_xh_kernel(
    const float* __restrict__ in, u16* __restrict__ ohi, u16* __restrict__ olo)
{
    __shared__ float tile[32][68];
    int z = blockIdx.y >> 2, cg = blockIdx.y & 3;
    int n0 = blockIdx.x * 64;
    int t = threadIdx.x;
    {
        int i = t >> 3, nc = (t & 7) * 8;
        const float* src = &in[((size_t)z*128 + cg*32 + i)*NN + n0 + nc];
        float4 a = *(const float4*)src;
        float4 b = *(const float4*)(src + 4);
        tile[i][nc+0]=a.x; tile[i][nc+1]=a.y; tile[i][nc+2]=a.z; tile[i][nc+3]=a.w;
        tile[i][nc+4]=b.x; tile[i][nc+5]=b.y; tile[i][nc+6]=b.z; tile[i][nc+7]=b.w;
    }
    __syncthreads();
    int n = t >> 2, c8 = (t & 3) * 8;
    short8 hi, lo;
    #pragma unroll
    for (int j = 0; j < 8; ++j) {
        float v = tile[c8 + j][n];
        u16 h = f2bf(v);
        hi[j] = (short)h;
        lo[j] = (short)f2bf(v - bf2f(h));
    }
    size_t ob = ((size_t)z*NN + n0 + n)*128 + cg*32 + c8;
    *(short8*)&ohi[ob] = hi;
    *(short8*)&olo[ob] = lo;
}

// ---------------------------------------------------------------------------
// shared 64x64 GEMM core, split-bf16 3-term, K-chunk 32, 4 waves 2x2 subtiles.
// T14: next K-chunk's global loads issued into registers during compute;
// only reg->LDS writes sit between barriers.
// ---------------------------------------------------------------------------
__device__ __forceinline__ void gcore(
    u16* As0, u16* As1, u16* Bs0, u16* Bs1,
    const u16* __restrict__ Whi, const u16* __restrict__ Wlo, int o0, int Cin,
    const u16* __restrict__ B1hi, const u16* __restrict__ B1lo, int s1,
    const u16* __restrict__ B2hi, const u16* __restrict__ B2lo, int s2, int split,
    size_t brow, int n0, const int* __restrict__ idxp, int t, f32x4 acc[2][2])
{
    const int lane = t & 63, w = t >> 6;
    const int l15 = lane & 15, quad = lane >> 4;
    const int wr = (w & 1)*32, wc = (w >> 1)*32;
    const int ao = t >> 2, ak = (t & 3)*8;
    int grow = n0 + ao;
    if (idxp) grow = idxp[grow];

    short8 rA0, rA1, rB0, rB1;
    {
        size_t wa = (size_t)(o0 + ao)*Cin + ak;
        rA0 = *(const short8*)&Whi[wa];
        rA1 = *(const short8*)&Wlo[wa];
        int c = ak;
        const u16 *ph, *pl; size_t off;
        if (c < split) { ph = B1hi; pl = B1lo; off = (brow + grow)*s1 + c; }
        else { ph = B2hi; pl = B2lo; off = (brow + grow)*s2 + (c - split); }
        rB0 = *(const short8*)&ph[off];
        rB1 = *(const short8*)&pl[off];
    }
    for (int kc = 0; kc < Cin; kc += 32) {
        __syncthreads();
        *(short8*)&As0[ao*40 + ak] = rA0;
        *(short8*)&As1[ao*40 + ak] = rA1;
        *(short8*)&Bs0[ao*40 + ak] = rB0;
        *(short8*)&Bs1[ao*40 + ak] = rB1;
        if (kc + 32 < Cin) {
            size_t wa = (size_t)(o0 + ao)*Cin + kc + 32 + ak;
            rA0 = *(const short8*)&Whi[wa];
            rA1 = *(const short8*)&Wlo[wa];
            int c = kc + 32 + ak;
            const u16 *ph, *pl; size_t off;
            if (c < split) { ph = B1hi; pl = B1lo; off = (brow + grow)*s1 + c; }
            else { ph = B2hi; pl = B2lo; off = (brow + grow)*s2 + (c - split); }
            rB0 = *(const short8*)&ph[off];
            rB1 = *(const short8*)&pl[off];
        }
        __syncthreads();
        short8 Ah[2], Al[2], Bh[2], Bl[2];
        #pragma unroll
        for (int a = 0; a < 2; ++a) {
            Ah[a] = *(const short8*)&As0[(wr + a*16 + l15)*40 + quad*8];
            Al[a] = *(const short8*)&As1[(wr + a*16 + l15)*40 + quad*8];
        }
        #pragma unroll
        for (int c = 0; c < 2; ++c) {
            Bh[c] = *(const short8*)&Bs0[(wc + c*16 + l15)*40 + quad*8];
            Bl[c] = *(const short8*)&Bs1[(wc + c*16 + l15)*40 + quad*8];
        }
        #pragma unroll
        for (int a = 0; a < 2; ++a)
            #pragma unroll
            for (int c = 0; c < 2; ++c) {
                acc[a][c] = __builtin_amdgcn_mfma_f32_16x16x32_bf16(Ah[a], Bl[c], acc[a][c], 0,0,0);
                acc[a][c] = __builtin_amdgcn_mfma_f32_16x16x32_bf16(Al[a], Bh[c], acc[a][c], 0,0,0);
                acc[a][c] = __builtin_amdgcn_mfma_f32_16x16x32_bf16(Ah[a], Bh[c], acc[a][c], 0,0,0);
            }
    }
    __syncthreads();
}

// ---------------------------------------------------------------------------
// Fused QKV, 64x64 tiles. bx<64: q role (2 row-tiles x 32 n-tiles, own x).
// else: k/v roles over gathered stream (idx indirection), n-tiles of M/64.
// Epilogues: q/k -> qt/kt planes [zh][C][32]; v -> vt hi [zh][32][M].
// q gets QK_SCALE (exp2-domain: includes log2e).
// ---------------------------------------------------------------------------
__global__ __launch_bounds__(256) void qkv_kernel(
    const u16* __restrict__ Whi, const u16* __restrict__ Wlo,
    const float* __restrict__ bqp, const float* __restrict__ bkp,
    const float* __restrict__ bvp,
    const u16* __restrict__ xphi, const u16* __restrict__ xplo,
    const int* __restrict__ idx0, const int* __restrict__ idx1,
    int cross, int M,
    u16* __restrict__ qthi, u16* __restrict__ qtlo,
    u16* __restrict__ kthi, u16* __restrict__ ktlo,
    u16* __restrict__ vthi, float* __restrict__ p)
{
    __shared__ u16 gsm[10240];
    u16* As0 = gsm;  u16* As1 = gsm + 2560;
    u16* Bs0 = gsm + 5120; u16* Bs1 = gsm + 7680;
    float* tb = (float*)gsm;                 // [64][66]

    const int z = blockIdx.z;
    const int bx = blockIdx.x;
    const int t = threadIdx.x;
    const int lane = t & 63, w = t >> 6;
    const int l15 = lane & 15, quad = lane >> 4;
    const int wr = (w & 1)*32, wc = (w >> 1)*32;

    int role, o0, n0, nCols;
    const u16 *Wbh, *Wbl;
    const float* bias;
    if (bx < 64) {
        role = 0; o0 = (bx & 1)*64; n0 = (bx >> 1)*64; nCols = NN;
        Wbh = Whi; Wbl = Wlo; bias = bqp;
        if (t < 32) p[(size_t)z*NN + bx*32 + t] = 0.f;
    } else {
        int e = bx - 64;
        int kt = M >> 6;
        int ct = e % kt, rt = e / kt;
        n0 = ct*64; nCols = M;
        if (rt < 2) { role = 1; o0 = rt*64; Wbh = Whi+16384; Wbl = Wlo+16384; bias = bkp; }
        else        { role = 2; o0 = (rt-2)*64; Wbh = Whi+32768; Wbl = Wlo+32768; bias = bvp; }
    }
    size_t brow = (size_t)z * NN;
    const int* idxp = nullptr;
    if (role != 0) {
        int ss = cross ? 1 - (z >> 1) : (z >> 1);
        brow = (size_t)(ss*2 + (z & 1)) * NN;
        idxp = (ss ? idx1 : idx0) + (z & 1)*NN;
    }

    f32x4 acc[2][2];
    #pragma unroll
    for (int a = 0; a < 2; ++a)
        #pragma unroll
        for (int c = 0; c < 2; ++c) acc[a][c] = (f32x4){0.f,0.f,0.f,0.f};

    gcore(As0, As1, Bs0, Bs1, Wbh, Wbl, o0, 128,
          xphi, xplo, 128, xphi, xplo, 128, 128, brow, n0, idxp, t, acc);

    if (role == 2) {
        #pragma unroll
        for (int a = 0; a < 2; ++a)
            #pragma unroll
            for (int c = 0; c < 2; ++c)
                #pragma unroll
                for (int r = 0; r < 4; ++r) {
                    int row = o0 + wr + a*16 + quad*4 + r;
                    int m = n0 + wc + c*16 + l15;
                    float v = acc[a][c][r] + bias[row];
                    vthi[((size_t)(z*4 + (row>>5))*32 + (row&31))*(size_t)M + m] = f2bf(v);
                }
    } else {
        float scale = role ? 1.f : QK_SCALE;
        #pragma unroll
        for (int a = 0; a < 2; ++a)
            #pragma unroll
            for (int c = 0; c < 2; ++c)
                #pragma unroll
                for (int r = 0; r < 4; ++r) {
                    int rl = wr + a*16 + quad*4 + r;
                    tb[rl*66 + wc + c*16 + l15] = acc[a][c][r] + bias[o0 + rl];
                }
        __syncthreads();
        u16* ohi = role ? kthi : qthi;
        u16* olo = role ? ktlo : qtlo;
        int n = t >> 2, rb = (t & 3)*16;
        #pragma unroll
        for (int g = 0; g < 2; ++g) {
            short8 hi, lo;
            #pragma unroll
            for (int j = 0; j < 8; ++j) {
                float v = tb[(rb + g*8 + j)*66 + n] * scale;
                u16 hb = f2bf(v);
                hi[j] = (short)hb;
                lo[j] = (short)f2bf(v - bf2f(hb));
            }
            int rowg = o0 + rb + g*8;
            size_t ob = ((size_t)(z*4 + (rowg >> 5))*nCols + n0 + n)*32 + (rowg & 31);
            *(short8*)&ohi[ob] = hi;
            *(short8*)&olo[ob] = lo;
        }
    }
}

// ---------------------------------------------------------------------------
// Attention v7: QBLK=32, 512 threads, 8 waves = (qh = w&1 q-16-tile,
// mh = w>>1 m-quarter). Grid 64 x NH x 4 = 1024 blocks = 4/CU. Chunk 128.
// BOTH passes 3-term split-bf16 scores, exp2 domain, T14 async staging.
// Pass 2: probs -> pcol (iv inside); PV operand-swapped via cvt_pk_bf16 +
// ds_bpermute; 1/l in epilogue.
// ---------------------------------------------------------------------------
__global__ __launch_bounds__(512, 8) void attn4_kernel(
    const u16* __restrict__ qthi, const u16* __restrict__ qtlo,
    const u16* __restrict__ kthi, const u16* __restrict__ ktlo,
    const u16* __restrict__ vthi, int M,
    u16* __restrict__ msghi, u16* __restrict__ msglo, float* __restrict__ p)
{
    __shared__ u16 kv[14592];            // ks0[128][40] | ks1[128][40] | vs[32][136]
    __shared__ float pcol[2048];
    __shared__ float redm[4][32], redl[4][32];
    __shared__ float rowM[32], rowIV[32];

    u16* ks0 = kv;
    u16* ks1 = kv + 5120;
    u16* vs  = kv + 10240;               // stride 136
    float* obuf = (float*)kv;            // [3*32][34] partials, then [32][34]

    const int t = threadIdx.x;
    const int lane = t & 63, wave = t >> 6;
    const int l15 = lane & 15, quad = lane >> 4;
    const int qh = wave & 1, mh = wave >> 1;     // mh 0..3
    const int h = blockIdx.y, z = blockIdx.z;
    const int zh = z*4 + h;
    const int n0 = blockIdx.x * 32;

    for (int i = t; i < M; i += 512) pcol[i] = 0.f;

    short8 qBh, qBl;
    {
        size_t qb = ((size_t)zh*NN + n0 + qh*16 + l15)*32 + quad*8;
        qBh = *(const short8*)&qthi[qb];
        qBl = *(const short8*)&qtlo[qb];
    }

    const int nch = M >> 7;
    const int sr = t >> 2, sc8 = (t & 3)*8;
    const int vr = t >> 4, vc8 = (t & 15)*8;

    float rm = -1e30f, rl = 0.f;

    // staged-load registers (T14): hold chunk data from issue to LDS-write
    short8 skh, skl, sv;
    {
        size_t gk = ((size_t)zh*M + sr)*32 + sc8;
        skh = *(const short8*)&kthi[gk];
        skl = *(const short8*)&ktlo[gk];
    }

    // ---- pass 1: (m,l) from 3-term scores (fp32-grade, exp2 domain) ----
    for (int ch = 0; ch < nch; ++ch) {
        __syncthreads();                     // prev chunk's readers done
        *(short8*)&ks0[sr*40 + sc8] = skh;
        *(short8*)&ks1[sr*40 + sc8] = skl;
        if (ch + 1 < nch) {
            size_t gk = ((size_t)zh*M + ((ch+1) << 7) + sr)*32 + sc8;
            skh = *(const short8*)&kthi[gk];   // in flight across compute
            skl = *(const short8*)&ktlo[gk];
        }
        __syncthreads();
        #pragma unroll
        for (int mt = 0; mt < 2; ++mt) {
            int mrow = mh*32 + mt*16 + l15;
            short8 kh = *(const short8*)&ks0[mrow*40 + quad*8];
            short8 kl = *(const short8*)&ks1[mrow*40 + quad*8];
            f32x4 a = {0.f,0.f,0.f,0.f};
            a = __builtin_amdgcn_mfma_f32_16x16x32_bf16(kh, qBl, a, 0,0,0);
            a = __builtin_amdgcn_mfma_f32_16x16x32_bf16(kl, qBh, a, 0,0,0);
            a = __builtin_amdgcn_mfma_f32_16x16x32_bf16(kh, qBh, a, 0,0,0);
            float bm = fmaxf(fmaxf(a[0],a[1]), fmaxf(a[2],a[3]));
            float bs = fexp2(a[0]-bm)+fexp2(a[1]-bm)+fexp2(a[2]-bm)+fexp2(a[3]-bm);
            if (bm > rm) { rl = rl*fexp2(rm-bm) + bs; rm = bm; }
            else rl += bs*fexp2(bm - rm);
        }
    }

    // issue pass-2 chunk-0 loads now; latency hides under the (m,l) reduction
    {
        size_t gk = ((size_t)zh*M + sr)*32 + sc8;
        skh = *(const short8*)&kthi[gk];
        skl = *(const short8*)&ktlo[gk];
        sv  = *(const short8*)&vthi[((size_t)zh*32 + vr)*M + vc8];
    }

    {
        #pragma unroll
        for (int off = 16; off <= 32; off <<= 1) {
            float om = __shfl_xor(rm, off);
            float ol = __shfl_xor(rl, off);
            float nm = fmaxf(rm, om);
            rl = rl*fexp2(rm-nm) + ol*fexp2(om-nm);
            rm = nm;
        }
        if (quad == 0) {
            redm[mh][qh*16 + l15] = rm;
            redl[mh][qh*16 + l15] = rl;
        }
    }
    __syncthreads();
    if (t < 32) {
        float m = redm[0][t], l = redl[0][t];
        #pragma unroll
        for (int w2 = 1; w2 < 4; ++w2) {
            float om = redm[w2][t];
            float nm = fmaxf(m, om);
            l = l*fexp2(m - nm) + redl[w2][t]*fexp2(om - nm);
            m = nm;
        }
        rowM[t] = m;
        rowIV[t] = 1.f / l;
    }
    __syncthreads();
    float myRM  = rowM[qh*16 + l15];
    float myRIV = rowIV[qh*16 + l15];

    // ---- pass 2: probs (3-term), pcol, swapped PV (bf16, unnormalized) ----
    f32x4 oa[2];
    #pragma unroll
    for (int dt = 0; dt < 2; ++dt) oa[dt] = (f32x4){0.f,0.f,0.f,0.f};

    const int aA = (l15 + 32*(quad & 1))*4;    // src lane (l15, quad'=2*(quad&1))
    const int aB = aA + 64;                    // src lane +16
    const bool mtsel = (quad >= 2);            // this quad consumes mt=1 data

    for (int ch = 0; ch < nch; ++ch) {
        const int m0 = ch << 7;
        __syncthreads();                     // prev chunk readers done
        *(short8*)&ks0[sr*40 + sc8] = skh;
        *(short8*)&ks1[sr*40 + sc8] = skl;
        *(short8*)&vs[vr*136 + vc8] = sv;
        if (ch + 1 < nch) {
            int m1 = (ch+1) << 7;
            size_t gk = ((size_t)zh*M + m1 + sr)*32 + sc8;
            skh = *(const short8*)&kthi[gk];
            skl = *(const short8*)&ktlo[gk];
            sv  = *(const short8*)&vthi[((size_t)zh*32 + vr)*M + m1 + vc8];
        }
        __syncthreads();

        float pr[2][4];
        #pragma unroll
        for (int mt = 0; mt < 2; ++mt) {
            int mrow = mh*32 + mt*16 + l15;
            short8 kh = *(const short8*)&ks0[mrow*40 + quad*8];
            short8 kl = *(const short8*)&ks1[mrow*40 + quad*8];
            f32x4 a = {0.f,0.f,0.f,0.f};
            a = __builtin_amdgcn_mfma_f32_16x16x32_bf16(kh, qBl, a, 0,0,0);
            a = __builtin_amdgcn_mfma_f32_16x16x32_bf16(kl, qBh, a, 0,0,0);
            a = __builtin_amdgcn_mfma_f32_16x16x32_bf16(kh, qBh, a, 0,0,0);
            #pragma unroll
            for (int r = 0; r < 4; ++r)
                pr[mt][r] = fexp2(a[r] - myRM);   // no iv here
        }

        // pcol: iv applied here so the pooling statistic p is unchanged
        #pragma unroll
        for (int mt = 0; mt < 2; ++mt)
            #pragma unroll
            for (int r = 0; r < 4; ++r) {
                float ps = pr[mt][r]*myRIV;
                ps += __shfl_xor(ps, 1);
                ps += __shfl_xor(ps, 2);
                ps += __shfl_xor(ps, 4);
                ps += __shfl_xor(ps, 8);
                if (l15 == 0)
                    atomicAdd(&pcol[m0 + mh*32 + mt*16 + quad*4 + r], ps);
            }

        short8 vA[2];
        #pragma unroll
        for (int dt = 0; dt < 2; ++dt)
            vA[dt] = *(const short8*)&vs[(dt*16 + l15)*136 + mh*32 + quad*8];

        // P^T B-frag in registers: pack -> quad-exchange -> swapped PV MFMA
        {
            unsigned pk00 = cvtpk_bf16(pr[0][0], pr[0][1]);
            unsigned pk01 = cvtpk_bf16(pr[0][2], pr[0][3]);
            unsigned pk10 = cvtpk_bf16(pr[1][0], pr[1][1]);
            unsigned pk11 = cvtpk_bf16(pr[1][2], pr[1][3]);
            unsigned a0 = (unsigned)__builtin_amdgcn_ds_bpermute(aA, (int)pk00);
            unsigned a1 = (unsigned)__builtin_amdgcn_ds_bpermute(aA, (int)pk01);
            unsigned a2 = (unsigned)__builtin_amdgcn_ds_bpermute(aA, (int)pk10);
            unsigned a3 = (unsigned)__builtin_amdgcn_ds_bpermute(aA, (int)pk11);
            unsigned b0 = (unsigned)__builtin_amdgcn_ds_bpermute(aB, (int)pk00);
            unsigned b1 = (unsigned)__builtin_amdgcn_ds_bpermute(aB, (int)pk01);
            unsigned b2 = (unsigned)__builtin_amdgcn_ds_bpermute(aB, (int)pk10);
            unsigned b3 = (unsigned)__builtin_amdgcn_ds_bpermute(aB, (int)pk11);
            union { unsigned u[4]; short8 s; } fb;
            fb.u[0] = mtsel ? a2 : a0;
            fb.u[1] = mtsel ? a3 : a1;
            fb.u[2] = mtsel ? b2 : b0;
            fb.u[3] = mtsel ? b3 : b1;
            #pragma unroll
            for (int dt = 0; dt < 2; ++dt)
                oa[dt] = __builtin_amdgcn_mfma_f32_16x16x32_bf16(vA[dt], fb.s, oa[dt], 0,0,0);
        }
    }
    __syncthreads();                         // last chunk readers done (obuf aliases kv)

    // merge mh partial PV sums via obuf [d][34-padded q] (aliases kv),
    // apply 1/l, pack msg planes. C-layout: q = col (l15), d = quad*4+r.
    if (mh > 0) {
        #pragma unroll
        for (int dt = 0; dt < 2; ++dt)
            #pragma unroll
            for (int r = 0; r < 4; ++r) {
                int q = qh*16 + l15;
                int d = dt*16 + quad*4 + r;
                obuf[((mh-1)*32 + d)*34 + q] = oa[dt][r];
            }
    }
    __syncthreads();
    if (mh == 0) {
        #pragma unroll
        for (int dt = 0; dt < 2; ++dt)
            #pragma unroll
            for (int r = 0; r < 4; ++r) {
                int q = qh*16 + l15;
                int d = dt*16 + quad*4 + r;
                float v = oa[dt][r];
                #pragma unroll
                for (int w2 = 0; w2 < 3; ++w2)
                    v += obuf[(w2*32 + d)*34 + q];
                obuf[d*34 + q] = v * myRIV;
            }
    }
    __syncthreads();
    if (t < 256) {
        int which = t >> 7;                  // 0: hi, 1: lo
        int tt = t & 127;
        int n = tt >> 2, i8 = (tt & 3)*8;    // n 0..31, i8 0..24
        short8 o8;
        if (which == 0) {
            #pragma unroll
            for (int j = 0; j < 8; ++j) o8[j] = (short)f2bf(obuf[(i8+j)*34 + n]);
            *(short8*)&msghi[((size_t)z*NN + n0 + n)*128 + h*32 + i8] = o8;
        } else {
            #pragma unroll
            for (int j = 0; j < 8; ++j) {
                float v = obuf[(i8+j)*34 + n];
                u16 hb = f2bf(v);
                o8[j] = (short)f2bf(v - bf2f(hb));
            }
            *(short8*)&msglo[((size_t)z*NN + n0 + n)*128 + h*32 + i8] = o8;
        }
    }
    for (int i = t; i < M; i += 512)
        atomicAdd(&p[(size_t)z*NN + i], pcol[i]*0.25f);
}

// ---------------------------------------------------------------------------
// Wm: m2 = Wm' * msg + bm -> m2 planes (epilogue transpose). Zeroes stats.
// ---------------------------------------------------------------------------
__global__ __launch_bounds__(256) void wm_kernel(
    const u16* __restrict__ Wmh, const u16* __restrict__ Wml,
    const float* __restrict__ bm,
    const u16* __restrict__ msghi, const u16* __restrict__ msglo,
    u16* __restrict__ m2hi, u16* __restrict__ m2lo,
    float* __restrict__ gsum, float* __restrict__ gsq)
{
    __shared__ u16 gsm[10240];
    u16* As0 = gsm;  u16* As1 = gsm + 2560;
    u16* Bs0 = gsm + 5120; u16* Bs1 = gsm + 7680;
    float* tb = (float*)gsm;

    const int z = blockIdx.z, o0 = blockIdx.y*64, n0 = blockIdx.x*64;
    const int t = threadIdx.x;
    const int lane = t & 63, w = t >> 6;
    const int l15 = lane & 15, quad = lane >> 4;
    const int wr = (w & 1)*32, wc = (w >> 1)*32;

    if (blockIdx.x == 0 && blockIdx.y == 0) {
        gsum[z*256 + t] = 0.f;
        gsq[z*256 + t] = 0.f;
    }

    f32x4 acc[2][2];
    #pragma unroll
    for (int a = 0; a < 2; ++a)
        #pragma unroll
        for (int c = 0; c < 2; ++c) acc[a][c] = (f32x4){0.f,0.f,0.f,0.f};
    gcore(As0, As1, Bs0, Bs1, Wmh, Wml, o0, 128,
          msghi, msglo, 128, msghi, msglo, 128, 128,
          (size_t)z*NN, n0, nullptr, t, acc);

    #pragma unroll
    for (int a = 0; a < 2; ++a)
        #pragma unroll
        for (int c = 0; c < 2; ++c)
            #pragma unroll
            for (int r = 0; r < 4; ++r) {
                int rl = wr + a*16 + quad*4 + r;
                tb[rl*66 + wc + c*16 + l15] = acc[a][c][r] + bm[o0 + rl];
            }
    __syncthreads();
    int n = t >> 2, rb = (t & 3)*16;
    #pragma unroll
    for (int g = 0; g < 2; ++g) {
        short8 hi, lo;
        #pragma unroll
        for (int j = 0; j < 8; ++j) {
            float v = tb[(rb + g*8 + j)*66 + n];
            u16 hb = f2bf(v);
            hi[j] = (short)hb;
            lo[j] = (short)f2bf(v - bf2f(hb));
        }
        size_t ob = ((size_t)z*NN + n0 + n)*128 + o0 + rb + g*8;
        *(short8*)&m2hi[ob] = hi;
        *(short8*)&m2lo[ob] = lo;
    }
}

// ---------------------------------------------------------------------------
// W1: z = W1 [x ; m2] + b1 -> zf fp32 + instnorm stats atomics.
// ---------------------------------------------------------------------------
__global__ __launch_bounds__(256) void w1_kernel(
    const u16* __restrict__ W1h, const u16* __restrict__ W1l,
    const float* __restrict__ b1,
    const u16* __restrict__ xphi, const u16* __restrict__ xplo,
    const u16* __restrict__ m2hi, const u16* __restrict__ m2lo,
    float* __restrict__ zf, float* __restrict__ gsum, float* __restrict__ gsq)
{
    __shared__ u16 gsm[10240];
    u16* As0 = gsm;  u16* As1 = gsm + 2560;
    u16* Bs0 = gsm + 5120; u16* Bs1 = gsm + 7680;

    const int z = blockIdx.z, o0 = blockIdx.y*64, n0 = blockIdx.x*64;
    const int t = threadIdx.x;
    const int lane = t & 63, w = t >> 6;
    const int l15 = lane & 15, quad = lane >> 4;
    const int wr = (w & 1)*32, wc = (w >> 1)*32;

    f32x4 acc[2][2];
    #pragma unroll
    for (int a = 0; a < 2; ++a)
        #pragma unroll
        for (int c = 0; c < 2; ++c) acc[a][c] = (f32x4){0.f,0.f,0.f,0.f};
    gcore(As0, As1, Bs0, Bs1, W1h, W1l, o0, 256,
          xphi, xplo, 128, m2hi, m2lo, 128, 128,
          (size_t)z*NN, n0, nullptr, t, acc);

    float ssum[2][4], ssq[2][4];
    #pragma unroll
    for (int a = 0; a < 2; ++a)
        #pragma unroll
        for (int r = 0; r < 4; ++r) { ssum[a][r] = 0.f; ssq[a][r] = 0.f; }
    #pragma unroll
    for (int a = 0; a < 2; ++a)
        #pragma unroll
        for (int c = 0; c < 2; ++c)
            #pragma unroll
            for (int r = 0; r < 4; ++r) {
                int row = o0 + wr + a*16 + quad*4 + r;
                int n = n0 + wc + c*16 + l15;
                float v = acc[a][c][r] + b1[row];
                zf[((size_t)z*256 + row)*NN + n] = v;
                ssum[a][r] += v;
                ssq[a][r] = fmaf(v, v, ssq[a][r]);
            }
    #pragma unroll
    for (int a = 0; a < 2; ++a)
        #pragma unroll
        for (int r = 0; r < 4; ++r) {
            float s = ssum[a][r], q2 = ssq[a][r];
            #pragma unroll
            for (int o = 1; o < 16; o <<= 1) {
                s  += __shfl_xor(s, o);
                q2 += __shfl_xor(q2, o);
            }
            if (l15 == 0) {
                int row = o0 + wr + a*16 + quad*4 + r;
                atomicAdd(&gsum[z*256 + row], s);
                atomicAdd(&gsq[z*256 + row], q2);
            }
        }
}

// ---------------------------------------------------------------------------
// h = relu(instnorm(zf)) -> h planes [z][n][256] hi/lo
// ---------------------------------------------------------------------------
__global__ __launch_bounds__(256) void hrepack_kernel(
    const float* __restrict__ zf, const float* __restrict__ gsum,
    const float* __restrict__ gsq, u16* __restrict__ hhi, u16* __restrict__ hlo)
{
    __shared__ float tile[32][68];
    int z = blockIdx.y >> 3, cg = blockIdx.y & 7;
    int n0 = blockIdx.x * 64;
    int t = threadIdx.x;
    {
        int i = t >> 3, nc = (t & 7) * 8;
        int c = cg*32 + i;
        float mean = gsum[z*256 + c] * (1.f/NN);
        float var = gsq[z*256 + c] * (1.f/NN) - mean*mean;
        float iv = rsqrtf(var + IN_EPS);
        const float* src = &zf[((size_t)z*256 + c)*NN + n0 + nc];
        float4 a = *(const float4*)src;
        float4 b = *(const float4*)(src + 4);
        float vv[8] = {a.x,a.y,a.z,a.w,b.x,b.y,b.z,b.w};
        #pragma unroll
        for (int j = 0; j < 8; ++j) {
            float v = (vv[j] - mean) * iv;
            tile[i][nc + j] = v > 0.f ? v : 0.f;
        }
    }
    __syncthreads();
    int n = t >> 2, c8 = (t & 3) * 8;
    short8 hi, lo;
    #pragma unroll
    for (int j = 0; j < 8; ++j) {
        float v = tile[c8 + j][n];
        u16 hb = f2bf(v);
        hi[j] = (short)hb;
        lo[j] = (short)f2bf(v - bf2f(hb));
    }
    size_t ob = ((size_t)z*NN + n0 + n)*256 + cg*32 + c8;
    *(short8*)&hhi[ob] = hi;
    *(short8*)&hlo[ob] = lo;
}

// ---------------------------------------------------------------------------
// W2: x += W2 h + b2 (fp32) and refresh x planes (unless last layer).
// ---------------------------------------------------------------------------
__global__ __launch_bounds__(256) void w2_kernel(
    const u16* __restrict__ W2h, const u16* __restrict__ W2l,
    const float* __restrict__ b2,
    const u16* __restrict__ hhi, const u16* __restrict__ hlo,
    float* __restrict__ out, u16* __restrict__ xphi, u16* __restrict__ xplo,
    int writeplanes)
{
    __shared__ u16 gsm[10240];
    u16* As0 = gsm;  u16* As1 = gsm + 2560;
    u16* Bs0 = gsm + 5120; u16* Bs1 = gsm + 7680;
    float* tb = (float*)gsm;

    const int z = blockIdx.z, o0 = blockIdx.y*64, n0 = blockIdx.x*64;
    const int t = threadIdx.x;
    const int lane = t & 63, w = t >> 6;
    const int l15 = lane & 15, quad = lane >> 4;
    const int wr = (w & 1)*32, wc = (w >> 1)*32;

    f32x4 acc[2][2];
    #pragma unroll
    for (int a = 0; a < 2; ++a)
        #pragma unroll
        for (int c = 0; c < 2; ++c) acc[a][c] = (f32x4){0.f,0.f,0.f,0.f};
    gcore(As0, As1, Bs0, Bs1, W2h, W2l, o0, 256,
          hhi, hlo, 256, hhi, hlo, 256, 256,
          (size_t)z*NN, n0, nullptr, t, acc);

    #pragma unroll
    for (int a = 0; a < 2; ++a)
        #pragma unroll
        for (int c = 0; c < 2; ++c)
            #pragma unroll
            for (int r = 0; r < 4; ++r) {
                int rl = wr + a*16 + quad*4 + r;
                int rowg = o0 + rl;
                int n = n0 + wc + c*16 + l15;
                size_t oi = ((size_t)z*128 + rowg)*NN + n;
                float v = acc[a][c][r] + b2[rowg] + out[oi];
                out[oi] = v;
                tb[rl*66 + wc + c*16 + l15] = v;
            }
    __syncthreads();
    if (writeplanes) {
        int n = t >> 2, rb = (t & 3)*16;
        #pragma unroll
        for (int g = 0; g < 2; ++g) {
            short8 hi, lo;
            #pragma unroll
            for (int j = 0; j < 8; ++j) {
                float v = tb[(rb + g*8 + j)*66 + n];
                u16 hb = f2bf(v);
                hi[j] = (short)hb;
                lo[j] = (short)f2bf(v - bf2f(hb));
            }
            size_t ob = ((size_t)z*NN + n0 + n)*128 + o0 + rb + g*8;
            *(short8*)&xphi[ob] = hi;
            *(short8*)&xplo[ob] = lo;
        }
    }
}

// ---------------------------------------------------------------------------
__global__ __launch_bounds__(256) void rank_kernel(
    const float* __restrict__ p, int* __restrict__ rank, int M)
{
    int zz = blockIdx.y;
    __shared__ float pv[2048];
    for (int i = threadIdx.x; i < M; i += 256) pv[i] = p[(size_t)zz*NN + i];
    __syncthreads();
    int i = blockIdx.x * 256 + threadIdx.x;
    if (i < M) {
        float pi = pv[i];
        int r = 0;
        for (int j = 0; j < M; ++j) {
            float pj = pv[j];
            r += (pj > pi) ? 1 : ((pj == pi && j < i) ? 1 : 0);
        }
        rank[zz*NN + i] = r;
    }
}

__global__ __launch_bounds__(256) void select_kernel(
    const int* __restrict__ rank, int* __restrict__ idx0, int* __restrict__ idx1,
    int M, int k, int cross)
{
    int z = blockIdx.x;
    int st = z >> 1, b = z & 1;
    int ts = cross ? 1 - st : st;
    int* idx = (ts ? idx1 : idx0) + b * NN;
    const int* rk = rank + z * NN;
    __shared__ int sel[2048], idv[2048], sa[2048], sb[2048];
    int t = threadIdx.x;
    for (int i = t; i < M; i += 256) {
        int s = rk[i] < k ? 1 : 0;
        sel[i] = s;
        sa[i] = s;
        idv[i] = idx[i];
    }
    __syncthreads();
    int* src = sa; int* dst = sb;
    for (int off = 1; off < M; off <<= 1) {
        for (int i = t; i < M; i += 256)
            dst[i] = src[i] + (i >= off ? src[i - off] : 0);
        __syncthreads();
        int* tmp = src; src = dst; dst = tmp;
    }
    for (int i = t; i < M; i += 256)
        if (sel[i]) idx[src[i] - 1] = idv[i];
}

// ---------------------------------------------------------------------------
extern "C" void kernel_launch(void* const* d_in, const int* in_sizes, int n_in,
                              void* d_out, int out_size, void* d_ws, size_t ws_size,
                              hipStream_t stream)
{
    const float* x0in = (const float*)d_in[0];
    const float* x1in = (const float*)d_in[1];
    const float* Wq = (const float*)d_in[2];
    const float* bq = (const float*)d_in[3];
    const float* Wk = (const float*)d_in[4];
    const float* bk = (const float*)d_in[5];
    const float* Wv = (const float*)d_in[6];
    const float* bv = (const float*)d_in[7];
    const float* Wm = (const float*)d_in[8];
    const float* bm = (const float*)d_in[9];
    const float* W1 = (const float*)d_in[10];
    const float* b1 = (const float*)d_in[11];
    const float* W2 = (const float*)d_in[12];
    const float* b2 = (const float*)d_in[13];

    float* out = (float*)d_out;
    float* ws  = (float*)d_ws;

    const size_t U = 1048576;
    u16* ub   = (u16*)ws;
    u16* xphi = ub;            u16* xplo = ub + U;
    u16* qthi = ub + 2*U;      u16* qtlo = ub + 3*U;
    u16* kthi = ub + 4*U;      u16* ktlo = ub + 5*U;
    u16* vthi = ub + 6*U;
    u16* msghi = ub + 7*U;     u16* msglo = ub + 8*U;
    u16* m2hi = ub + 9*U;      u16* m2lo = ub + 10*U;
    u16* hhi  = ub + 11*U;     u16* hlo = ub + 13*U;      // 2U each
    u16* whi  = ub + 15*U;     u16* wlo = whi + 655360;
    float* zf = (float*)(ub + 2*U);                        // aliases qt/kt (8 MB)
    float* ft = (float*)(wlo + 655360);
    float* bqp = ft;           float* bkp = ft + 512;      float* bvp = ft + 1024;
    float* gsum = ft + 1536;   float* gsq = ft + 2560;
    float* p = ft + 3584;                                  // [4][NN]
    int* idx0 = (int*)(p + 4*NN);
    int* idx1 = idx0 + NB*NN;
    int* rankb = idx1 + NB*NN;

    init_kernel<<<BDN/4/256, 256, 0, stream>>>(x0in, x1in, out, idx0, idx1);
    wrepack2_kernel<<<2566, 256, 0, stream>>>(Wq, Wk, Wv, Wm, W1, W2, bq, bk, bv,
                                              whi, wlo, bqp, bkp, bvp);
    repack_xh_kernel<<<dim3(32, 16), 256, 0, stream>>>(out, xphi, xplo);

    const int Ms[4] = {2048, 1024, 512, 256};
    for (int l = 0; l < 4; ++l) {
        int M = Ms[l];
        int k_new = (M/2 < 128) ? 128 : M/2;
        int cross = l & 1;
        size_t lw = (size_t)l * 163840;
        const u16* Wlh = whi + lw;  const u16* Wll = wlo + lw;

        qkv_kernel<<<dim3(64 + 4*(M/64), 1, 4), 256, 0, stream>>>(
            Wlh, Wll, bqp + l*128, bkp + l*128, bvp + l*128,
            xphi, xplo, idx0, idx1, cross, M,
            qthi, qtlo, kthi, ktlo, vthi, p);

        attn4_kernel<<<dim3(64, NH, 4), 512, 0, stream>>>(
            qthi, qtlo, kthi, ktlo, vthi, M, msghi, msglo, p);

        wm_kernel<<<dim3(32, 2, 4), 256, 0, stream>>>(
            Wlh + 49152, Wll + 49152, bm + l*128,
            msghi, msglo, m2hi, m2lo, gsum, gsq);

        w1_kernel<<<dim3(32, 4, 4), 256, 0, stream>>>(
            Wlh + 65536, Wll + 65536, b1 + l*256,
            xphi, xplo, m2hi, m2lo, zf, gsum, gsq);

        hrepack_kernel<<<dim3(32, 32), 256, 0, stream>>>(zf, gsum, gsq, hhi, hlo);

        w2_kernel<<<dim3(32, 2, 4), 256, 0, stream>>>(
            Wlh + 131072, Wll + 131072, b2 + l*128,
            hhi, hlo, out, xphi, xplo, (l < 3) ? 1 : 0);

        rank_kernel<<<dim3((M+255)/256, 4), 256, 0, stream>>>(p, rankb, M);
        select_kernel<<<4, 256, 0, stream>>>(rankb, idx0, idx1, M, k_new, cross);
    }
}

// Round 4
// 532.960 us; speedup vs baseline: 1.2348x; 1.2348x over previous
//
#include <hip/hip_runtime.h>
#include <cstdint>
#include <cstddef>

// ---------------------------------------------------------------------------
// SDHGNN round 12: revert to round-10 geometry (QBLK=64, 512 attn blocks,
// best known 542 us), then remove attn4's K/V LDS staging entirely:
//  - K/V for one (z,h) is 256+128 KB, L2-resident; per-chunk K working set
//    16 KB fits L1 -> direct global loads (coalesced 1KB segments) replace
//    the global->reg->LDS->reg path. Zero chunk barriers, zero staging
//    instructions, bank conflicts ~gone (guide common-mistake #7 / m169).
//  - T5 s_setprio around MFMA clusters (waves free-run -> arbitration helps).
//  - obuf gets a dedicated LDS array; block LDS ~36 KB.
//  - gcore/GEMM kernels IDENTICAL to round 10 (one structural change/round).
// ---------------------------------------------------------------------------

#define NB 2
#define ND 128
#define NH 4
#define NN 2048
#define ND2 256
#define DN (ND*NN)
#define BDN (NB*DN)
// (1/sqrt(32)) * log2(e): scores produced directly in exp2 domain.
#define QK_SCALE 0.2550348623f
#define IN_EPS 1e-3f

typedef unsigned short u16;
typedef __attribute__((ext_vector_type(8))) short short8;
typedef __attribute__((ext_vector_type(4))) float f32x4;

__device__ __forceinline__ u16 f2bf(float f) {
    unsigned u = __float_as_uint(f);
    return (u16)((u + 0x7fffu + ((u >> 16) & 1u)) >> 16);
}
__device__ __forceinline__ float bf2f(u16 h) {
    return __uint_as_float(((unsigned)h) << 16);
}
__device__ __forceinline__ float fexp2(float x) {
#if __has_builtin(__builtin_amdgcn_exp2f)
    return __builtin_amdgcn_exp2f(x);
#else
    return exp2f(x);
#endif
}
__device__ __forceinline__ unsigned cvtpk_bf16(float a, float b) {
    unsigned r;
    asm("v_cvt_pk_bf16_f32 %0, %1, %2" : "=v"(r) : "v"(a), "v"(b));
    return r;
}

// ---------------------------------------------------------------------------
__global__ __launch_bounds__(256) void init_kernel(
    const float* __restrict__ x0in, const float* __restrict__ x1in,
    float* __restrict__ out, int* __restrict__ idx0, int* __restrict__ idx1)
{
    int tid = blockIdx.x * 256 + threadIdx.x;
    const float4* a = (const float4*)x0in;
    const float4* b = (const float4*)x1in;
    float4* o = (float4*)out;
    o[tid] = a[tid];
    o[BDN/4 + tid] = b[tid];
    if (tid < NB*NN) {
        int v = tid & (NN-1);
        idx0[tid] = v;
        idx1[tid] = v;
    }
}

// ---------------------------------------------------------------------------
// weights -> bf16 hi/lo planes with permutations:
//   Wq/Wk/Wv rows permuted o' = h*32+i; Wm cols permuted; W1/W2 unchanged.
// ---------------------------------------------------------------------------
__global__ __launch_bounds__(256) void wrepack2_kernel(
    const float* __restrict__ Wq, const float* __restrict__ Wk,
    const float* __restrict__ Wv, const float* __restrict__ Wm,
    const float* __restrict__ W1, const float* __restrict__ W2,
    const float* __restrict__ bq, const float* __restrict__ bk,
    const float* __restrict__ bv,
    u16* __restrict__ whi, u16* __restrict__ wlo,
    float* __restrict__ bqp, float* __restrict__ bkp, float* __restrict__ bvp)
{
    int e = blockIdx.x * 256 + threadIdx.x;
    if (e < 655360) {
        int l = e / 163840, r = e - l*163840;
        float v;
        if (r < 49152) {
            int m = r >> 14;
            int rr = r & 16383;
            int o = rr >> 7, c = rr & 127;
            int so = (o & 31)*4 + (o >> 5);
            const float* W = (m == 0) ? Wq : ((m == 1) ? Wk : Wv);
            v = W[l*16384 + so*128 + c];
        } else if (r < 65536) {
            int rr = r - 49152;
            int o = rr >> 7, c = rr & 127;
            int sc = (c & 31)*4 + (c >> 5);
            v = Wm[l*16384 + o*128 + sc];
        } else if (r < 131072) v = W1[l*65536 + r - 65536];
        else                   v = W2[l*32768 + r - 131072];
        u16 hb = f2bf(v);
        whi[e] = hb;
        wlo[e] = f2bf(v - bf2f(hb));
    } else if (e < 656896) {
        int eb = e - 655360;
        int l = eb / 384, rr = eb % 384;
        int which = rr >> 7, o = rr & 127;
        int so = (o & 31)*4 + (o >> 5);
        float v = (which == 0 ? bq : (which == 1 ? bk : bv))[l*128 + so];
        (which == 0 ? bqp : (which == 1 ? bkp : bvp))[l*128 + o] = v;
    }
}

// ---------------------------------------------------------------------------
// fp32 [z][128][NN] -> bf16 hi/lo planes [z][n][128] (initial x planes)
// ---------------------------------------------------------------------------
__global__ __launch_bounds__(256) void repack_xh_kernel(
    const float* __restrict__ in, u16* __restrict__ ohi, u16* __restrict__ olo)
{
    __shared__ float tile[32][68];
    int z = blockIdx.y >> 2, cg = blockIdx.y & 3;
    int n0 = blockIdx.x * 64;
    int t = threadIdx.x;
    {
        int i = t >> 3, nc = (t & 7) * 8;
        const float* src = &in[((size_t)z*128 + cg*32 + i)*NN + n0 + nc];
        float4 a = *(const float4*)src;
        float4 b = *(const float4*)(src + 4);
        tile[i][nc+0]=a.x; tile[i][nc+1]=a.y; tile[i][nc+2]=a.z; tile[i][nc+3]=a.w;
        tile[i][nc+4]=b.x; tile[i][nc+5]=b.y; tile[i][nc+6]=b.z; tile[i][nc+7]=b.w;
    }
    __syncthreads();
    int n = t >> 2, c8 = (t & 3) * 8;
    short8 hi, lo;
    #pragma unroll
    for (int j = 0; j < 8; ++j) {
        float v = tile[c8 + j][n];
        u16 h = f2bf(v);
        hi[j] = (short)h;
        lo[j] = (short)f2bf(v - bf2f(h));
    }
    size_t ob = ((size_t)z*NN + n0 + n)*128 + cg*32 + c8;
    *(short8*)&ohi[ob] = hi;
    *(short8*)&olo[ob] = lo;
}

// ---------------------------------------------------------------------------
// shared 64x64 GEMM core, split-bf16 3-term, K-chunk 32, 4 waves 2x2 subtiles.
// T14: next K-chunk's global loads issued into registers during compute;
// only reg->LDS writes sit between barriers. (unchanged from round 10)
// ---------------------------------------------------------------------------
__device__ __forceinline__ void gcore(
    u16* As0, u16* As1, u16* Bs0, u16* Bs1,
    const u16* __restrict__ Whi, const u16* __restrict__ Wlo, int o0, int Cin,
    const u16* __restrict__ B1hi, const u16* __restrict__ B1lo, int s1,
    const u16* __restrict__ B2hi, const u16* __restrict__ B2lo, int s2, int split,
    size_t brow, int n0, const int* __restrict__ idxp, int t, f32x4 acc[2][2])
{
    const int lane = t & 63, w = t >> 6;
    const int l15 = lane & 15, quad = lane >> 4;
    const int wr = (w & 1)*32, wc = (w >> 1)*32;
    const int ao = t >> 2, ak = (t & 3)*8;
    int grow = n0 + ao;
    if (idxp) grow = idxp[grow];

    short8 rA0, rA1, rB0, rB1;
    {
        size_t wa = (size_t)(o0 + ao)*Cin + ak;
        rA0 = *(const short8*)&Whi[wa];
        rA1 = *(const short8*)&Wlo[wa];
        int c = ak;
        const u16 *ph, *pl; size_t off;
        if (c < split) { ph = B1hi; pl = B1lo; off = (brow + grow)*s1 + c; }
        else { ph = B2hi; pl = B2lo; off = (brow + grow)*s2 + (c - split); }
        rB0 = *(const short8*)&ph[off];
        rB1 = *(const short8*)&pl[off];
    }
    for (int kc = 0; kc < Cin; kc += 32) {
        __syncthreads();
        *(short8*)&As0[ao*40 + ak] = rA0;
        *(short8*)&As1[ao*40 + ak] = rA1;
        *(short8*)&Bs0[ao*40 + ak] = rB0;
        *(short8*)&Bs1[ao*40 + ak] = rB1;
        if (kc + 32 < Cin) {
            size_t wa = (size_t)(o0 + ao)*Cin + kc + 32 + ak;
            rA0 = *(const short8*)&Whi[wa];
            rA1 = *(const short8*)&Wlo[wa];
            int c = kc + 32 + ak;
            const u16 *ph, *pl; size_t off;
            if (c < split) { ph = B1hi; pl = B1lo; off = (brow + grow)*s1 + c; }
            else { ph = B2hi; pl = B2lo; off = (brow + grow)*s2 + (c - split); }
            rB0 = *(const short8*)&ph[off];
            rB1 = *(const short8*)&pl[off];
        }
        __syncthreads();
        short8 Ah[2], Al[2], Bh[2], Bl[2];
        #pragma unroll
        for (int a = 0; a < 2; ++a) {
            Ah[a] = *(const short8*)&As0[(wr + a*16 + l15)*40 + quad*8];
            Al[a] = *(const short8*)&As1[(wr + a*16 + l15)*40 + quad*8];
        }
        #pragma unroll
        for (int c = 0; c < 2; ++c) {
            Bh[c] = *(const short8*)&Bs0[(wc + c*16 + l15)*40 + quad*8];
            Bl[c] = *(const short8*)&Bs1[(wc + c*16 + l15)*40 + quad*8];
        }
        #pragma unroll
        for (int a = 0; a < 2; ++a)
            #pragma unroll
            for (int c = 0; c < 2; ++c) {
                acc[a][c] = __builtin_amdgcn_mfma_f32_16x16x32_bf16(Ah[a], Bl[c], acc[a][c], 0,0,0);
                acc[a][c] = __builtin_amdgcn_mfma_f32_16x16x32_bf16(Al[a], Bh[c], acc[a][c], 0,0,0);
                acc[a][c] = __builtin_amdgcn_mfma_f32_16x16x32_bf16(Ah[a], Bh[c], acc[a][c], 0,0,0);
            }
    }
    __syncthreads();
}

// ---------------------------------------------------------------------------
// Fused QKV, 64x64 tiles. bx<64: q role (2 row-tiles x 32 n-tiles, own x).
// else: k/v roles over gathered stream (idx indirection), n-tiles of M/64.
// Epilogues: q/k -> qt/kt planes [zh][C][32]; v -> vt hi [zh][32][M].
// q gets QK_SCALE (exp2-domain: includes log2e).
// ---------------------------------------------------------------------------
__global__ __launch_bounds__(256) void qkv_kernel(
    const u16* __restrict__ Whi, const u16* __restrict__ Wlo,
    const float* __restrict__ bqp, const float* __restrict__ bkp,
    const float* __restrict__ bvp,
    const u16* __restrict__ xphi, const u16* __restrict__ xplo,
    const int* __restrict__ idx0, const int* __restrict__ idx1,
    int cross, int M,
    u16* __restrict__ qthi, u16* __restrict__ qtlo,
    u16* __restrict__ kthi, u16* __restrict__ ktlo,
    u16* __restrict__ vthi, float* __restrict__ p)
{
    __shared__ u16 gsm[10240];
    u16* As0 = gsm;  u16* As1 = gsm + 2560;
    u16* Bs0 = gsm + 5120; u16* Bs1 = gsm + 7680;
    float* tb = (float*)gsm;                 // [64][66]

    const int z = blockIdx.z;
    const int bx = blockIdx.x;
    const int t = threadIdx.x;
    const int lane = t & 63, w = t >> 6;
    const int l15 = lane & 15, quad = lane >> 4;
    const int wr = (w & 1)*32, wc = (w >> 1)*32;

    int role, o0, n0, nCols;
    const u16 *Wbh, *Wbl;
    const float* bias;
    if (bx < 64) {
        role = 0; o0 = (bx & 1)*64; n0 = (bx >> 1)*64; nCols = NN;
        Wbh = Whi; Wbl = Wlo; bias = bqp;
        if (t < 32) p[(size_t)z*NN + bx*32 + t] = 0.f;
    } else {
        int e = bx - 64;
        int kt = M >> 6;
        int ct = e % kt, rt = e / kt;
        n0 = ct*64; nCols = M;
        if (rt < 2) { role = 1; o0 = rt*64; Wbh = Whi+16384; Wbl = Wlo+16384; bias = bkp; }
        else        { role = 2; o0 = (rt-2)*64; Wbh = Whi+32768; Wbl = Wlo+32768; bias = bvp; }
    }
    size_t brow = (size_t)z * NN;
    const int* idxp = nullptr;
    if (role != 0) {
        int ss = cross ? 1 - (z >> 1) : (z >> 1);
        brow = (size_t)(ss*2 + (z & 1)) * NN;
        idxp = (ss ? idx1 : idx0) + (z & 1)*NN;
    }

    f32x4 acc[2][2];
    #pragma unroll
    for (int a = 0; a < 2; ++a)
        #pragma unroll
        for (int c = 0; c < 2; ++c) acc[a][c] = (f32x4){0.f,0.f,0.f,0.f};

    gcore(As0, As1, Bs0, Bs1, Wbh, Wbl, o0, 128,
          xphi, xplo, 128, xphi, xplo, 128, 128, brow, n0, idxp, t, acc);

    if (role == 2) {
        #pragma unroll
        for (int a = 0; a < 2; ++a)
            #pragma unroll
            for (int c = 0; c < 2; ++c)
                #pragma unroll
                for (int r = 0; r < 4; ++r) {
                    int row = o0 + wr + a*16 + quad*4 + r;
                    int m = n0 + wc + c*16 + l15;
                    float v = acc[a][c][r] + bias[row];
                    vthi[((size_t)(z*4 + (row>>5))*32 + (row&31))*(size_t)M + m] = f2bf(v);
                }
    } else {
        float scale = role ? 1.f : QK_SCALE;
        #pragma unroll
        for (int a = 0; a < 2; ++a)
            #pragma unroll
            for (int c = 0; c < 2; ++c)
                #pragma unroll
                for (int r = 0; r < 4; ++r) {
                    int rl = wr + a*16 + quad*4 + r;
                    tb[rl*66 + wc + c*16 + l15] = acc[a][c][r] + bias[o0 + rl];
                }
        __syncthreads();
        u16* ohi = role ? kthi : qthi;
        u16* olo = role ? ktlo : qtlo;
        int n = t >> 2, rb = (t & 3)*16;
        #pragma unroll
        for (int g = 0; g < 2; ++g) {
            short8 hi, lo;
            #pragma unroll
            for (int j = 0; j < 8; ++j) {
                float v = tb[(rb + g*8 + j)*66 + n] * scale;
                u16 hb = f2bf(v);
                hi[j] = (short)hb;
                lo[j] = (short)f2bf(v - bf2f(hb));
            }
            int rowg = o0 + rb + g*8;
            size_t ob = ((size_t)(z*4 + (rowg >> 5))*nCols + n0 + n)*32 + (rowg & 31);
            *(short8*)&ohi[ob] = hi;
            *(short8*)&olo[ob] = lo;
        }
    }
}

// ---------------------------------------------------------------------------
// Attention v8: QBLK=64, 512 threads, 8 waves (qp = w&1 q-half, mh = w>>1
// m-quarter). NO K/V LDS staging: K/V are L2/L1-resident; direct global
// loads per chunk, zero chunk barriers. BOTH passes 3-term split-bf16
// scores, exp2 domain. Pass 2: probs -> pcol (iv inside); PV operand-swapped
// via cvt_pk_bf16 + ds_bpermute; 1/l in epilogue. setprio around MFMA.
// ---------------------------------------------------------------------------
__global__ __launch_bounds__(512, 4) void attn4_kernel(
    const u16* __restrict__ qthi, const u16* __restrict__ qtlo,
    const u16* __restrict__ kthi, const u16* __restrict__ ktlo,
    const u16* __restrict__ vthi, int M,
    u16* __restrict__ msghi, u16* __restrict__ msglo, float* __restrict__ p)
{
    __shared__ float pcol[2048];
    __shared__ float obuf[96*66];        // mh-partial merge + msg pack (25.3 KB)
    __shared__ float redm[4][64], redl[4][64];
    __shared__ float rowM[64], rowIV[64];

    const int t = threadIdx.x;
    const int lane = t & 63, wave = t >> 6;
    const int l15 = lane & 15, quad = lane >> 4;
    const int qp = wave & 1, mh = wave >> 1;     // mh 0..3
    const int h = blockIdx.y, z = blockIdx.z;
    const int zh = z*4 + h;
    const int n0 = blockIdx.x * 64;

    for (int i = t; i < M; i += 512) pcol[i] = 0.f;

    short8 qBh[2], qBl[2];
    #pragma unroll
    for (int qt = 0; qt < 2; ++qt) {
        size_t qb = ((size_t)zh*NN + n0 + qp*32 + qt*16 + l15)*32 + quad*8;
        qBh[qt] = *(const short8*)&qthi[qb];
        qBl[qt] = *(const short8*)&qtlo[qb];
    }

    const int nch = M >> 7;
    // direct-load bases: K row = ch*128 + mh*32 + mt*16 + l15, 16B col = quad
    const size_t kb0 = ((size_t)zh*M + mh*32 + l15)*32 + quad*8;
    const u16* kbh = kthi + kb0;
    const u16* kbl = ktlo + kb0;
    // V row = dt*16 + l15, col = ch*128 + mh*32 + quad*8
    const u16* vb = vthi + ((size_t)zh*32 + l15)*M + mh*32 + quad*8;

    float rm[2] = {-1e30f, -1e30f}, rl[2] = {0.f, 0.f};

    // ---- pass 1: (m,l) from 3-term scores (fp32-grade, exp2 domain) ----
    for (int ch = 0; ch < nch; ++ch) {
        const int co = ch*128*32;
        #pragma unroll
        for (int mt = 0; mt < 2; ++mt) {
            short8 kh = *(const short8*)&kbh[co + mt*512];
            short8 kl = *(const short8*)&kbl[co + mt*512];
            __builtin_amdgcn_s_setprio(1);
            f32x4 av[2];
            #pragma unroll
            for (int qt = 0; qt < 2; ++qt) {
                f32x4 a = {0.f,0.f,0.f,0.f};
                a = __builtin_amdgcn_mfma_f32_16x16x32_bf16(kh, qBl[qt], a, 0,0,0);
                a = __builtin_amdgcn_mfma_f32_16x16x32_bf16(kl, qBh[qt], a, 0,0,0);
                a = __builtin_amdgcn_mfma_f32_16x16x32_bf16(kh, qBh[qt], a, 0,0,0);
                av[qt] = a;
            }
            __builtin_amdgcn_s_setprio(0);
            #pragma unroll
            for (int qt = 0; qt < 2; ++qt) {
                f32x4 a = av[qt];
                float bm = fmaxf(fmaxf(a[0],a[1]), fmaxf(a[2],a[3]));
                float bs = fexp2(a[0]-bm)+fexp2(a[1]-bm)+fexp2(a[2]-bm)+fexp2(a[3]-bm);
                if (bm > rm[qt]) { rl[qt] = rl[qt]*fexp2(rm[qt]-bm) + bs; rm[qt] = bm; }
                else rl[qt] += bs*fexp2(bm - rm[qt]);
            }
        }
    }

    #pragma unroll
    for (int qt = 0; qt < 2; ++qt) {
        #pragma unroll
        for (int off = 16; off <= 32; off <<= 1) {
            float om = __shfl_xor(rm[qt], off);
            float ol = __shfl_xor(rl[qt], off);
            float nm = fmaxf(rm[qt], om);
            rl[qt] = rl[qt]*fexp2(rm[qt]-nm) + ol*fexp2(om-nm);
            rm[qt] = nm;
        }
        if (quad == 0) {
            redm[mh][qp*32 + qt*16 + l15] = rm[qt];
            redl[mh][qp*32 + qt*16 + l15] = rl[qt];
        }
    }
    __syncthreads();
    if (t < 64) {
        float m = redm[0][t], l = redl[0][t];
        #pragma unroll
        for (int w2 = 1; w2 < 4; ++w2) {
            float om = redm[w2][t];
            float nm = fmaxf(m, om);
            l = l*fexp2(m - nm) + redl[w2][t]*fexp2(om - nm);
            m = nm;
        }
        rowM[t] = m;
        rowIV[t] = 1.f / l;
    }
    __syncthreads();
    float myRM[2], myRIV[2];
    #pragma unroll
    for (int qt = 0; qt < 2; ++qt) {
        myRM[qt]  = rowM[qp*32 + qt*16 + l15];
        myRIV[qt] = rowIV[qp*32 + qt*16 + l15];
    }

    // ---- pass 2: probs (3-term), pcol, swapped PV (bf16, unnormalized) ----
    f32x4 oa[2][2];
    #pragma unroll
    for (int qt = 0; qt < 2; ++qt)
        #pragma unroll
        for (int dt = 0; dt < 2; ++dt) oa[qt][dt] = (f32x4){0.f,0.f,0.f,0.f};

    const int aA = (l15 + 32*(quad & 1))*4;    // src lane (l15, quad'=2*(quad&1))
    const int aB = aA + 64;                    // src lane +16
    const bool mtsel = (quad >= 2);            // this quad consumes mt=1 data

    for (int ch = 0; ch < nch; ++ch) {
        const int m0 = ch << 7;
        const int co = ch*128*32;

        float pr[2][2][4];
        #pragma unroll
        for (int mt = 0; mt < 2; ++mt) {
            short8 kh = *(const short8*)&kbh[co + mt*512];
            short8 kl = *(const short8*)&kbl[co + mt*512];
            __builtin_amdgcn_s_setprio(1);
            f32x4 av[2];
            #pragma unroll
            for (int qt = 0; qt < 2; ++qt) {
                f32x4 a = {0.f,0.f,0.f,0.f};
                a = __builtin_amdgcn_mfma_f32_16x16x32_bf16(kh, qBl[qt], a, 0,0,0);
                a = __builtin_amdgcn_mfma_f32_16x16x32_bf16(kl, qBh[qt], a, 0,0,0);
                a = __builtin_amdgcn_mfma_f32_16x16x32_bf16(kh, qBh[qt], a, 0,0,0);
                av[qt] = a;
            }
            __builtin_amdgcn_s_setprio(0);
            #pragma unroll
            for (int qt = 0; qt < 2; ++qt)
                #pragma unroll
                for (int r = 0; r < 4; ++r)
                    pr[qt][mt][r] = fexp2(av[qt][r] - myRM[qt]);   // no iv here
        }

        // pcol: iv applied here so the pooling statistic p is unchanged
        #pragma unroll
        for (int mt = 0; mt < 2; ++mt)
            #pragma unroll
            for (int r = 0; r < 4; ++r) {
                float ps = pr[0][mt][r]*myRIV[0] + pr[1][mt][r]*myRIV[1];
                ps += __shfl_xor(ps, 1);
                ps += __shfl_xor(ps, 2);
                ps += __shfl_xor(ps, 4);
                ps += __shfl_xor(ps, 8);
                if (l15 == 0)
                    atomicAdd(&pcol[m0 + mh*32 + mt*16 + quad*4 + r], ps);
            }

        short8 vA[2];
        #pragma unroll
        for (int dt = 0; dt < 2; ++dt)
            vA[dt] = *(const short8*)&vb[(size_t)dt*16*M + m0];

        // P^T B-frag in registers: pack -> quad-exchange -> swapped PV MFMA
        #pragma unroll
        for (int qt = 0; qt < 2; ++qt) {
            unsigned pk00 = cvtpk_bf16(pr[qt][0][0], pr[qt][0][1]);
            unsigned pk01 = cvtpk_bf16(pr[qt][0][2], pr[qt][0][3]);
            unsigned pk10 = cvtpk_bf16(pr[qt][1][0], pr[qt][1][1]);
            unsigned pk11 = cvtpk_bf16(pr[qt][1][2], pr[qt][1][3]);
            unsigned a0 = (unsigned)__builtin_amdgcn_ds_bpermute(aA, (int)pk00);
            unsigned a1 = (unsigned)__builtin_amdgcn_ds_bpermute(aA, (int)pk01);
            unsigned a2 = (unsigned)__builtin_amdgcn_ds_bpermute(aA, (int)pk10);
            unsigned a3 = (unsigned)__builtin_amdgcn_ds_bpermute(aA, (int)pk11);
            unsigned b0 = (unsigned)__builtin_amdgcn_ds_bpermute(aB, (int)pk00);
            unsigned b1 = (unsigned)__builtin_amdgcn_ds_bpermute(aB, (int)pk01);
            unsigned b2 = (unsigned)__builtin_amdgcn_ds_bpermute(aB, (int)pk10);
            unsigned b3 = (unsigned)__builtin_amdgcn_ds_bpermute(aB, (int)pk11);
            union { unsigned u[4]; short8 s; } fb;
            fb.u[0] = mtsel ? a2 : a0;
            fb.u[1] = mtsel ? a3 : a1;
            fb.u[2] = mtsel ? b2 : b0;
            fb.u[3] = mtsel ? b3 : b1;
            __builtin_amdgcn_s_setprio(1);
            #pragma unroll
            for (int dt = 0; dt < 2; ++dt)
                oa[qt][dt] = __builtin_amdgcn_mfma_f32_16x16x32_bf16(vA[dt], fb.s, oa[qt][dt], 0,0,0);
            __builtin_amdgcn_s_setprio(0);
        }
    }

    // merge mh partial PV sums via obuf [d][66-padded q],
    // apply 1/l, pack msg planes. C-layout: q = col (l15), d = quad*4+r.
    if (mh > 0) {
        #pragma unroll
        for (int qt = 0; qt < 2; ++qt)
            #pragma unroll
            for (int dt = 0; dt < 2; ++dt)
                #pragma unroll
                for (int r = 0; r < 4; ++r) {
                    int q = qp*32 + qt*16 + l15;
                    int d = dt*16 + quad*4 + r;
                    obuf[((mh-1)*32 + d)*66 + q] = oa[qt][dt][r];
                }
    }
    __syncthreads();
    if (mh == 0) {
        #pragma unroll
        for (int qt = 0; qt < 2; ++qt)
            #pragma unroll
            for (int dt = 0; dt < 2; ++dt)
                #pragma unroll
                for (int r = 0; r < 4; ++r) {
                    int q = qp*32 + qt*16 + l15;
                    int d = dt*16 + quad*4 + r;
                    float v = oa[qt][dt][r];
                    #pragma unroll
                    for (int w2 = 0; w2 < 3; ++w2)
                        v += obuf[(w2*32 + d)*66 + q];
                    obuf[d*66 + q] = v * myRIV[qt];
                }
    }
    __syncthreads();
    {
        int tt = t & 255;
        int n = tt >> 2, i8 = (tt & 3)*8;
        short8 o8;
        if (t < 256) {
            #pragma unroll
            for (int j = 0; j < 8; ++j) o8[j] = (short)f2bf(obuf[(i8+j)*66 + n]);
            *(short8*)&msghi[((size_t)z*NN + n0 + n)*128 + h*32 + i8] = o8;
        } else {
            #pragma unroll
            for (int j = 0; j < 8; ++j) {
                float v = obuf[(i8+j)*66 + n];
                u16 hb = f2bf(v);
                o8[j] = (short)f2bf(v - bf2f(hb));
            }
            *(short8*)&msglo[((size_t)z*NN + n0 + n)*128 + h*32 + i8] = o8;
        }
    }
    for (int i = t; i < M; i += 512)
        atomicAdd(&p[(size_t)z*NN + i], pcol[i]*0.25f);
}

// ---------------------------------------------------------------------------
// Wm: m2 = Wm' * msg + bm -> m2 planes (epilogue transpose). Zeroes stats.
// ---------------------------------------------------------------------------
__global__ __launch_bounds__(256) void wm_kernel(
    const u16* __restrict__ Wmh, const u16* __restrict__ Wml,
    const float* __restrict__ bm,
    const u16* __restrict__ msghi, const u16* __restrict__ msglo,
    u16* __restrict__ m2hi, u16* __restrict__ m2lo,
    float* __restrict__ gsum, float* __restrict__ gsq)
{
    __shared__ u16 gsm[10240];
    u16* As0 = gsm;  u16* As1 = gsm + 2560;
    u16* Bs0 = gsm + 5120; u16* Bs1 = gsm + 7680;
    float* tb = (float*)gsm;

    const int z = blockIdx.z, o0 = blockIdx.y*64, n0 = blockIdx.x*64;
    const int t = threadIdx.x;
    const int lane = t & 63, w = t >> 6;
    const int l15 = lane & 15, quad = lane >> 4;
    const int wr = (w & 1)*32, wc = (w >> 1)*32;

    if (blockIdx.x == 0 && blockIdx.y == 0) {
        gsum[z*256 + t] = 0.f;
        gsq[z*256 + t] = 0.f;
    }

    f32x4 acc[2][2];
    #pragma unroll
    for (int a = 0; a < 2; ++a)
        #pragma unroll
        for (int c = 0; c < 2; ++c) acc[a][c] = (f32x4){0.f,0.f,0.f,0.f};
    gcore(As0, As1, Bs0, Bs1, Wmh, Wml, o0, 128,
          msghi, msglo, 128, msghi, msglo, 128, 128,
          (size_t)z*NN, n0, nullptr, t, acc);

    #pragma unroll
    for (int a = 0; a < 2; ++a)
        #pragma unroll
        for (int c = 0; c < 2; ++c)
            #pragma unroll
            for (int r = 0; r < 4; ++r) {
                int rl = wr + a*16 + quad*4 + r;
                tb[rl*66 + wc + c*16 + l15] = acc[a][c][r] + bm[o0 + rl];
            }
    __syncthreads();
    int n = t >> 2, rb = (t & 3)*16;
    #pragma unroll
    for (int g = 0; g < 2; ++g) {
        short8 hi, lo;
        #pragma unroll
        for (int j = 0; j < 8; ++j) {
            float v = tb[(rb + g*8 + j)*66 + n];
            u16 hb = f2bf(v);
            hi[j] = (short)hb;
            lo[j] = (short)f2bf(v - bf2f(hb));
        }
        size_t ob = ((size_t)z*NN + n0 + n)*128 + o0 + rb + g*8;
        *(short8*)&m2hi[ob] = hi;
        *(short8*)&m2lo[ob] = lo;
    }
}

// ---------------------------------------------------------------------------
// W1: z = W1 [x ; m2] + b1 -> zf fp32 + instnorm stats atomics.
// ---------------------------------------------------------------------------
__global__ __launch_bounds__(256) void w1_kernel(
    const u16* __restrict__ W1h, const u16* __restrict__ W1l,
    const float* __restrict__ b1,
    const u16* __restrict__ xphi, const u16* __restrict__ xplo,
    const u16* __restrict__ m2hi, const u16* __restrict__ m2lo,
    float* __restrict__ zf, float* __restrict__ gsum, float* __restrict__ gsq)
{
    __shared__ u16 gsm[10240];
    u16* As0 = gsm;  u16* As1 = gsm + 2560;
    u16* Bs0 = gsm + 5120; u16* Bs1 = gsm + 7680;

    const int z = blockIdx.z, o0 = blockIdx.y*64, n0 = blockIdx.x*64;
    const int t = threadIdx.x;
    const int lane = t & 63, w = t >> 6;
    const int l15 = lane & 15, quad = lane >> 4;
    const int wr = (w & 1)*32, wc = (w >> 1)*32;

    f32x4 acc[2][2];
    #pragma unroll
    for (int a = 0; a < 2; ++a)
        #pragma unroll
        for (int c = 0; c < 2; ++c) acc[a][c] = (f32x4){0.f,0.f,0.f,0.f};
    gcore(As0, As1, Bs0, Bs1, W1h, W1l, o0, 256,
          xphi, xplo, 128, m2hi, m2lo, 128, 128,
          (size_t)z*NN, n0, nullptr, t, acc);

    float ssum[2][4], ssq[2][4];
    #pragma unroll
    for (int a = 0; a < 2; ++a)
        #pragma unroll
        for (int r = 0; r < 4; ++r) { ssum[a][r] = 0.f; ssq[a][r] = 0.f; }
    #pragma unroll
    for (int a = 0; a < 2; ++a)
        #pragma unroll
        for (int c = 0; c < 2; ++c)
            #pragma unroll
            for (int r = 0; r < 4; ++r) {
                int row = o0 + wr + a*16 + quad*4 + r;
                int n = n0 + wc + c*16 + l15;
                float v = acc[a][c][r] + b1[row];
                zf[((size_t)z*256 + row)*NN + n] = v;
                ssum[a][r] += v;
                ssq[a][r] = fmaf(v, v, ssq[a][r]);
            }
    #pragma unroll
    for (int a = 0; a < 2; ++a)
        #pragma unroll
        for (int r = 0; r < 4; ++r) {
            float s = ssum[a][r], q2 = ssq[a][r];
            #pragma unroll
            for (int o = 1; o < 16; o <<= 1) {
                s  += __shfl_xor(s, o);
                q2 += __shfl_xor(q2, o);
            }
            if (l15 == 0) {
                int row = o0 + wr + a*16 + quad*4 + r;
                atomicAdd(&gsum[z*256 + row], s);
                atomicAdd(&gsq[z*256 + row], q2);
            }
        }
}

// ---------------------------------------------------------------------------
// h = relu(instnorm(zf)) -> h planes [z][n][256] hi/lo
// ---------------------------------------------------------------------------
__global__ __launch_bounds__(256) void hrepack_kernel(
    const float* __restrict__ zf, const float* __restrict__ gsum,
    const float* __restrict__ gsq, u16* __restrict__ hhi, u16* __restrict__ hlo)
{
    __shared__ float tile[32][68];
    int z = blockIdx.y >> 3, cg = blockIdx.y & 7;
    int n0 = blockIdx.x * 64;
    int t = threadIdx.x;
    {
        int i = t >> 3, nc = (t & 7) * 8;
        int c = cg*32 + i;
        float mean = gsum[z*256 + c] * (1.f/NN);
        float var = gsq[z*256 + c] * (1.f/NN) - mean*mean;
        float iv = rsqrtf(var + IN_EPS);
        const float* src = &zf[((size_t)z*256 + c)*NN + n0 + nc];
        float4 a = *(const float4*)src;
        float4 b = *(const float4*)(src + 4);
        float vv[8] = {a.x,a.y,a.z,a.w,b.x,b.y,b.z,b.w};
        #pragma unroll
        for (int j = 0; j < 8; ++j) {
            float v = (vv[j] - mean) * iv;
            tile[i][nc + j] = v > 0.f ? v : 0.f;
        }
    }
    __syncthreads();
    int n = t >> 2, c8 = (t & 3) * 8;
    short8 hi, lo;
    #pragma unroll
    for (int j = 0; j < 8; ++j) {
        float v = tile[c8 + j][n];
        u16 hb = f2bf(v);
        hi[j] = (short)hb;
        lo[j] = (short)f2bf(v - bf2f(hb));
    }
    size_t ob = ((size_t)z*NN + n0 + n)*256 + cg*32 + c8;
    *(short8*)&hhi[ob] = hi;
    *(short8*)&hlo[ob] = lo;
}

// ---------------------------------------------------------------------------
// W2: x += W2 h + b2 (fp32) and refresh x planes (unless last layer).
// ---------------------------------------------------------------------------
__global__ __launch_bounds__(256) void w2_kernel(
    const u16* __restrict__ W2h, const u16* __restrict__ W2l,
    const float* __restrict__ b2,
    const u16* __restrict__ hhi, const u16* __restrict__ hlo,
    float* __restrict__ out, u16* __restrict__ xphi, u16* __restrict__ xplo,
    int writeplanes)
{
    __shared__ u16 gsm[10240];
    u16* As0 = gsm;  u16* As1 = gsm + 2560;
    u16* Bs0 = gsm + 5120; u16* Bs1 = gsm + 7680;
    float* tb = (float*)gsm;

    const int z = blockIdx.z, o0 = blockIdx.y*64, n0 = blockIdx.x*64;
    const int t = threadIdx.x;
    const int lane = t & 63, w = t >> 6;
    const int l15 = lane & 15, quad = lane >> 4;
    const int wr = (w & 1)*32, wc = (w >> 1)*32;

    f32x4 acc[2][2];
    #pragma unroll
    for (int a = 0; a < 2; ++a)
        #pragma unroll
        for (int c = 0; c < 2; ++c) acc[a][c] = (f32x4){0.f,0.f,0.f,0.f};
    gcore(As0, As1, Bs0, Bs1, W2h, W2l, o0, 256,
          hhi, hlo, 256, hhi, hlo, 256, 256,
          (size_t)z*NN, n0, nullptr, t, acc);

    #pragma unroll
    for (int a = 0; a < 2; ++a)
        #pragma unroll
        for (int c = 0; c < 2; ++c)
            #pragma unroll
            for (int r = 0; r < 4; ++r) {
                int rl = wr + a*16 + quad*4 + r;
                int rowg = o0 + rl;
                int n = n0 + wc + c*16 + l15;
                size_t oi = ((size_t)z*128 + rowg)*NN + n;
                float v = acc[a][c][r] + b2[rowg] + out[oi];
                out[oi] = v;
                tb[rl*66 + wc + c*16 + l15] = v;
            }
    __syncthreads();
    if (writeplanes) {
        int n = t >> 2, rb = (t & 3)*16;
        #pragma unroll
        for (int g = 0; g < 2; ++g) {
            short8 hi, lo;
            #pragma unroll
            for (int j = 0; j < 8; ++j) {
                float v = tb[(rb + g*8 + j)*66 + n];
                u16 hb = f2bf(v);
                hi[j] = (short)hb;
                lo[j] = (short)f2bf(v - bf2f(hb));
            }
            size_t ob = ((size_t)z*NN + n0 + n)*128 + o0 + rb + g*8;
            *(short8*)&xphi[ob] = hi;
            *(short8*)&xplo[ob] = lo;
        }
    }
}

// ---------------------------------------------------------------------------
__global__ __launch_bounds__(256) void rank_kernel(
    const float* __restrict__ p, int* __restrict__ rank, int M)
{
    int zz = blockIdx.y;
    __shared__ float pv[2048];
    for (int i = threadIdx.x; i < M; i += 256) pv[i] = p[(size_t)zz*NN + i];
    __syncthreads();
    int i = blockIdx.x * 256 + threadIdx.x;
    if (i < M) {
        float pi = pv[i];
        int r = 0;
        for (int j = 0; j < M; ++j) {
            float pj = pv[j];
            r += (pj > pi) ? 1 : ((pj == pi && j < i) ? 1 : 0);
        }
        rank[zz*NN + i] = r;
    }
}

__global__ __launch_bounds__(256) void select_kernel(
    const int* __restrict__ rank, int* __restrict__ idx0, int* __restrict__ idx1,
    int M, int k, int cross)
{
    int z = blockIdx.x;
    int st = z >> 1, b = z & 1;
    int ts = cross ? 1 - st : st;
    int* idx = (ts ? idx1 : idx0) + b * NN;
    const int* rk = rank + z * NN;
    __shared__ int sel[2048], idv[2048], sa[2048], sb[2048];
    int t = threadIdx.x;
    for (int i = t; i < M; i += 256) {
        int s = rk[i] < k ? 1 : 0;
        sel[i] = s;
        sa[i] = s;
        idv[i] = idx[i];
    }
    __syncthreads();
    int* src = sa; int* dst = sb;
    for (int off = 1; off < M; off <<= 1) {
        for (int i = t; i < M; i += 256)
            dst[i] = src[i] + (i >= off ? src[i - off] : 0);
        __syncthreads();
        int* tmp = src; src = dst; dst = tmp;
    }
    for (int i = t; i < M; i += 256)
        if (sel[i]) idx[src[i] - 1] = idv[i];
}

// ---------------------------------------------------------------------------
extern "C" void kernel_launch(void* const* d_in, const int* in_sizes, int n_in,
                              void* d_out, int out_size, void* d_ws, size_t ws_size,
                              hipStream_t stream)
{
    const float* x0in = (const float*)d_in[0];
    const float* x1in = (const float*)d_in[1];
    const float* Wq = (const float*)d_in[2];
    const float* bq = (const float*)d_in[3];
    const float* Wk = (const float*)d_in[4];
    const float* bk = (const float*)d_in[5];
    const float* Wv = (const float*)d_in[6];
    const float* bv = (const float*)d_in[7];
    const float* Wm = (const float*)d_in[8];
    const float* bm = (const float*)d_in[9];
    const float* W1 = (const float*)d_in[10];
    const float* b1 = (const float*)d_in[11];
    const float* W2 = (const float*)d_in[12];
    const float* b2 = (const float*)d_in[13];

    float* out = (float*)d_out;
    float* ws  = (float*)d_ws;

    const size_t U = 1048576;
    u16* ub   = (u16*)ws;
    u16* xphi = ub;            u16* xplo = ub + U;
    u16* qthi = ub + 2*U;      u16* qtlo = ub + 3*U;
    u16* kthi = ub + 4*U;      u16* ktlo = ub + 5*U;
    u16* vthi = ub + 6*U;
    u16* msghi = ub + 7*U;     u16* msglo = ub + 8*U;
    u16* m2hi = ub + 9*U;      u16* m2lo = ub + 10*U;
    u16* hhi  = ub + 11*U;     u16* hlo = ub + 13*U;      // 2U each
    u16* whi  = ub + 15*U;     u16* wlo = whi + 655360;
    float* zf = (float*)(ub + 2*U);                        // aliases qt/kt (8 MB)
    float* ft = (float*)(wlo + 655360);
    float* bqp = ft;           float* bkp = ft + 512;      float* bvp = ft + 1024;
    float* gsum = ft + 1536;   float* gsq = ft + 2560;
    float* p = ft + 3584;                                  // [4][NN]
    int* idx0 = (int*)(p + 4*NN);
    int* idx1 = idx0 + NB*NN;
    int* rankb = idx1 + NB*NN;

    init_kernel<<<BDN/4/256, 256, 0, stream>>>(x0in, x1in, out, idx0, idx1);
    wrepack2_kernel<<<2566, 256, 0, stream>>>(Wq, Wk, Wv, Wm, W1, W2, bq, bk, bv,
                                              whi, wlo, bqp, bkp, bvp);
    repack_xh_kernel<<<dim3(32, 16), 256, 0, stream>>>(out, xphi, xplo);

    const int Ms[4] = {2048, 1024, 512, 256};
    for (int l = 0; l < 4; ++l) {
        int M = Ms[l];
        int k_new = (M/2 < 128) ? 128 : M/2;
        int cross = l & 1;
        size_t lw = (size_t)l * 163840;
        const u16* Wlh = whi + lw;  const u16* Wll = wlo + lw;

        qkv_kernel<<<dim3(64 + 4*(M/64), 1, 4), 256, 0, stream>>>(
            Wlh, Wll, bqp + l*128, bkp + l*128, bvp + l*128,
            xphi, xplo, idx0, idx1, cross, M,
            qthi, qtlo, kthi, ktlo, vthi, p);

        attn4_kernel<<<dim3(32, NH, 4), 512, 0, stream>>>(
            qthi, qtlo, kthi, ktlo, vthi, M, msghi, msglo, p);

        wm_kernel<<<dim3(32, 2, 4), 256, 0, stream>>>(
            Wlh + 49152, Wll + 49152, bm + l*128,
            msghi, msglo, m2hi, m2lo, gsum, gsq);

        w1_kernel<<<dim3(32, 4, 4), 256, 0, stream>>>(
            Wlh + 65536, Wll + 65536, b1 + l*256,
            xphi, xplo, m2hi, m2lo, zf, gsum, gsq);

        hrepack_kernel<<<dim3(32, 32), 256, 0, stream>>>(zf, gsum, gsq, hhi, hlo);

        w2_kernel<<<dim3(32, 2, 4), 256, 0, stream>>>(
            Wlh + 131072, Wll + 131072, b2 + l*128,
            hhi, hlo, out, xphi, xplo, (l < 3) ? 1 : 0);

        rank_kernel<<<dim3((M+255)/256, 4), 256, 0, stream>>>(p, rankb, M);
        select_kernel<<<4, 256, 0, stream>>>(rankb, idx0, idx1, M, k_new, cross);
    }
}